// Round 3
// baseline (2992.698 us; speedup 1.0000x reference)
//
#include <hip/hip_runtime.h>

typedef unsigned short u16;
typedef unsigned int   u32;
typedef __attribute__((ext_vector_type(8))) short short8;
typedef __attribute__((ext_vector_type(4))) float f32x4;

#define AS1 __attribute__((address_space(1)))
#define AS3 __attribute__((address_space(3)))

#define TOK   16384
#define DM    768
#define DFF   3072
#define DH    1536          // Dff half (two-pass MoE)
#define NEXP  8
#define ROWS  32768         // total routed rows = 2*TOK exactly

static __device__ __forceinline__ void gld16(const void* g, void* l) {
  __builtin_amdgcn_global_load_lds((const AS1 void*)g, (AS3 void*)l, 16, 0, 0);
}
static __device__ __forceinline__ u16 f2bf(float f) {
  u32 u = __float_as_uint(f);
  return (u16)((u + 0x7fffu + ((u >> 16) & 1u)) >> 16);  // RNE
}

// ---------------------------------------------------------------- small utils
// in: [z][R][C] fp32  ->  out: [z][C][R] bf16
__global__ __launch_bounds__(256) void transpose_cast_kernel(const float* __restrict__ in,
                                                             u16* __restrict__ out, int R, int C) {
  __shared__ float tile[32][33];
  const float* src = in + (size_t)blockIdx.z * R * C;
  u16* dst = out + (size_t)blockIdx.z * R * C;
  int tx = threadIdx.x, ty = threadIdx.y;
#pragma unroll
  for (int yy = 0; yy < 4; ++yy) {
    int r = blockIdx.y * 32 + ty + yy * 8;
    int c = blockIdx.x * 32 + tx;
    tile[ty + yy * 8][tx] = src[(size_t)r * C + c];
  }
  __syncthreads();
#pragma unroll
  for (int yy = 0; yy < 4; ++yy) {
    int oc = blockIdx.x * 32 + ty + yy * 8;   // output row (= input col)
    dst[(size_t)oc * R + blockIdx.y * 32 + tx] = f2bf(tile[tx][ty + yy * 8]);
  }
}

// LayerNorm over D=768, fp32 math. One block per token. Two output variants.
__global__ __launch_bounds__(256) void ln_f32_kernel(const float* __restrict__ x,
    const float* __restrict__ g, const float* __restrict__ b, float* __restrict__ out) {
  const int t = blockIdx.x;
  const int tid = threadIdx.x;
  const float* row = x + (size_t)t * DM;
  float v0 = row[tid], v1 = row[tid + 256], v2 = row[tid + 512];
  float s = v0 + v1 + v2;
  float s2 = v0 * v0 + v1 * v1 + v2 * v2;
#pragma unroll
  for (int off = 32; off > 0; off >>= 1) {
    s += __shfl_down(s, off, 64);
    s2 += __shfl_down(s2, off, 64);
  }
  __shared__ float red[8];
  if ((tid & 63) == 0) { red[tid >> 6] = s; red[4 + (tid >> 6)] = s2; }
  __syncthreads();
  float S = red[0] + red[1] + red[2] + red[3];
  float S2 = red[4] + red[5] + red[6] + red[7];
  float mean = S * (1.0f / DM);
  float var = S2 * (1.0f / DM) - mean * mean;
  float rstd = rsqrtf(var + 1e-5f);
  float* orow = out + (size_t)t * DM;
  orow[tid]       = (v0 - mean) * rstd * g[tid]       + b[tid];
  orow[tid + 256] = (v1 - mean) * rstd * g[tid + 256] + b[tid + 256];
  orow[tid + 512] = (v2 - mean) * rstd * g[tid + 512] + b[tid + 512];
}

__global__ __launch_bounds__(256) void ln_bf16_kernel(const float* __restrict__ x,
    const float* __restrict__ g, const float* __restrict__ b, u16* __restrict__ out) {
  const int t = blockIdx.x;
  const int tid = threadIdx.x;
  const float* row = x + (size_t)t * DM;
  float v0 = row[tid], v1 = row[tid + 256], v2 = row[tid + 512];
  float s = v0 + v1 + v2;
  float s2 = v0 * v0 + v1 * v1 + v2 * v2;
#pragma unroll
  for (int off = 32; off > 0; off >>= 1) {
    s += __shfl_down(s, off, 64);
    s2 += __shfl_down(s2, off, 64);
  }
  __shared__ float red[8];
  if ((tid & 63) == 0) { red[tid >> 6] = s; red[4 + (tid >> 6)] = s2; }
  __syncthreads();
  float S = red[0] + red[1] + red[2] + red[3];
  float S2 = red[4] + red[5] + red[6] + red[7];
  float mean = S * (1.0f / DM);
  float var = S2 * (1.0f / DM) - mean * mean;
  float rstd = rsqrtf(var + 1e-5f);
  u16* orow = out + (size_t)t * DM;
  orow[tid]       = f2bf((v0 - mean) * rstd * g[tid]       + b[tid]);
  orow[tid + 256] = f2bf((v1 - mean) * rstd * g[tid + 256] + b[tid + 256]);
  orow[tid + 512] = f2bf((v2 - mean) * rstd * g[tid + 512] + b[tid + 512]);
}

// -------------------------------------------------------- fp32 GEMM mainloop
// C[256x128] = A[M][K] * B[N][K]^T, all fp32. 256 threads, 16x8 per thread.
// BK=16. lsA [16][256], lsB [16][128] staged k-major.
// Thread (tm=tid>>4, tn=tid&15): rows {q*64 + tm*4 + j}, cols {h*64 + tn*4 + i}
// -> every ds_read_b128 is <=2-way bank-aliased (free), 6 LDS reads / 128 FMA.
__device__ __forceinline__ void sgemm_mainloop(const float* __restrict__ A,
    const float* __restrict__ B, int lda, int ldb, int gm0, int gn0, int K,
    float (*lsA)[256], float (*lsB)[128], float acc[16][8]) {
  const int tid = threadIdx.x;
  const int tm = tid >> 4, tn = tid & 15;
  const int brow = tid >> 1, bk8 = (tid & 1) * 8;
  const float* ga = A + (size_t)(gm0 + tid) * lda;
  const float* gb = B + (size_t)(gn0 + brow) * ldb + bk8;
  for (int k0 = 0; k0 < K; k0 += 16) {
    float4 a0 = *(const float4*)(ga + k0);
    float4 a1 = *(const float4*)(ga + k0 + 4);
    float4 a2 = *(const float4*)(ga + k0 + 8);
    float4 a3 = *(const float4*)(ga + k0 + 12);
    float4 b0 = *(const float4*)(gb + k0);
    float4 b1 = *(const float4*)(gb + k0 + 4);
    __syncthreads();   // previous compute done before overwrite
    lsA[0][tid]  = a0.x; lsA[1][tid]  = a0.y; lsA[2][tid]  = a0.z; lsA[3][tid]  = a0.w;
    lsA[4][tid]  = a1.x; lsA[5][tid]  = a1.y; lsA[6][tid]  = a1.z; lsA[7][tid]  = a1.w;
    lsA[8][tid]  = a2.x; lsA[9][tid]  = a2.y; lsA[10][tid] = a2.z; lsA[11][tid] = a2.w;
    lsA[12][tid] = a3.x; lsA[13][tid] = a3.y; lsA[14][tid] = a3.z; lsA[15][tid] = a3.w;
    lsB[bk8 + 0][brow] = b0.x; lsB[bk8 + 1][brow] = b0.y;
    lsB[bk8 + 2][brow] = b0.z; lsB[bk8 + 3][brow] = b0.w;
    lsB[bk8 + 4][brow] = b1.x; lsB[bk8 + 5][brow] = b1.y;
    lsB[bk8 + 6][brow] = b1.z; lsB[bk8 + 7][brow] = b1.w;
    __syncthreads();
#pragma unroll
    for (int k = 0; k < 16; ++k) {
      float4 av0 = *(const float4*)&lsA[k][tm * 4];
      float4 av1 = *(const float4*)&lsA[k][64 + tm * 4];
      float4 av2 = *(const float4*)&lsA[k][128 + tm * 4];
      float4 av3 = *(const float4*)&lsA[k][192 + tm * 4];
      float4 bv0 = *(const float4*)&lsB[k][tn * 4];
      float4 bv1 = *(const float4*)&lsB[k][64 + tn * 4];
      float av[16] = {av0.x, av0.y, av0.z, av0.w, av1.x, av1.y, av1.z, av1.w,
                      av2.x, av2.y, av2.z, av2.w, av3.x, av3.y, av3.z, av3.w};
      float bv[8]  = {bv0.x, bv0.y, bv0.z, bv0.w, bv1.x, bv1.y, bv1.z, bv1.w};
#pragma unroll
      for (int i = 0; i < 16; ++i)
#pragma unroll
        for (int j = 0; j < 8; ++j)
          acc[i][j] = fmaf(av[i], bv[j], acc[i][j]);
    }
  }
}

// QKV fp32: A=x2f[T][768], B=in_proj_w[2304][768]; scatter to q/k/v [B,H,S,64] fp32
__global__ __launch_bounds__(256, 2) void qkv_f32_kernel(const float* __restrict__ A,
    const float* __restrict__ Bw, const float* __restrict__ bias,
    float* __restrict__ qf, float* __restrict__ kf, float* __restrict__ vf) {
  __shared__ float lsA[16][256];
  __shared__ float lsB[16][128];
  const int gm0 = blockIdx.x * 256, gn0 = blockIdx.y * 128;
  float acc[16][8];
#pragma unroll
  for (int i = 0; i < 16; ++i)
#pragma unroll
    for (int j = 0; j < 8; ++j) acc[i][j] = 0.f;
  sgemm_mainloop(A, Bw, DM, DM, gm0, gn0, DM, lsA, lsB, acc);
  const int tm = threadIdx.x >> 4, tn = threadIdx.x & 15;
#pragma unroll
  for (int jj = 0; jj < 8; ++jj) {
    int col = gn0 + (jj >> 2) * 64 + tn * 4 + (jj & 3);
    int which = col / DM;
    int rem = col - which * DM;
    int hh = rem >> 6, dd = rem & 63;
    float bc = bias[col];
    float* dst = which == 0 ? qf : (which == 1 ? kf : vf);
#pragma unroll
    for (int ii = 0; ii < 16; ++ii) {
      int t = gm0 + (ii >> 2) * 64 + tm * 4 + (ii & 3);
      int bb = t >> 9, ss = t & 511;
      dst[(((size_t)(bb * 12 + hh) * 512 + ss) << 6) + dd] = acc[ii][jj] + bc;
    }
  }
}

// Out-proj fp32: A=aof[T][768], B=out_proj_w[768][768]; + bias + residual -> xres
__global__ __launch_bounds__(256, 2) void outproj_f32_kernel(const float* __restrict__ A,
    const float* __restrict__ Bw, const float* __restrict__ bias,
    const float* __restrict__ xin, float* __restrict__ xres) {
  __shared__ float lsA[16][256];
  __shared__ float lsB[16][128];
  const int gm0 = blockIdx.x * 256, gn0 = blockIdx.y * 128;
  float acc[16][8];
#pragma unroll
  for (int i = 0; i < 16; ++i)
#pragma unroll
    for (int j = 0; j < 8; ++j) acc[i][j] = 0.f;
  sgemm_mainloop(A, Bw, DM, DM, gm0, gn0, DM, lsA, lsB, acc);
  const int tm = threadIdx.x >> 4, tn = threadIdx.x & 15;
#pragma unroll
  for (int ii = 0; ii < 16; ++ii) {
    int t = gm0 + (ii >> 2) * 64 + tm * 4 + (ii & 3);
#pragma unroll
    for (int jj = 0; jj < 8; ++jj) {
      int n = gn0 + (jj >> 2) * 64 + tn * 4 + (jj & 3);
      size_t off = (size_t)t * DM + n;
      xres[off] = acc[ii][jj] + bias[n] + xin[off];
    }
  }
}

// ------------------------------------------------------------ fp32 attention
// One thread per query row. No cross-lane ops. Keys processed in chunks of 4:
// 8 independent dot chains (2 half-dots x 4 keys), one max/rescale per chunk
// (record-breaking chunks are rare: ~ln(128) of 128), 64 independent PV
// accumulator chains. q[64]+o[64] kept in VGPRs via __launch_bounds__(256,2).
__global__ __launch_bounds__(256, 2) void attn_f32_kernel(const float* __restrict__ qb,
    const float* __restrict__ kb, const float* __restrict__ vb, float* __restrict__ ao) {
  const int bh = blockIdx.x >> 1;
  const int sq = (blockIdx.x & 1) * 256 + threadIdx.x;
  const size_t base = (size_t)bh * 512 * 64;
  const float* qp = qb + base + (size_t)sq * 64;
  float q[64];
#pragma unroll
  for (int i = 0; i < 16; ++i) {
    float4 t = ((const float4*)qp)[i];
    q[4 * i]     = t.x * 0.125f;   // fold 1/sqrt(64)
    q[4 * i + 1] = t.y * 0.125f;
    q[4 * i + 2] = t.z * 0.125f;
    q[4 * i + 3] = t.w * 0.125f;
  }
  float m = -1e30f, l = 0.f, o[64];
#pragma unroll
  for (int d = 0; d < 64; ++d) o[d] = 0.f;
  const float4* kp = (const float4*)(kb + base);
  const float4* vp = (const float4*)(vb + base);
  for (int k0 = 0; k0 < 512; k0 += 4) {
    const float4* kr = kp + (size_t)k0 * 16;   // 4 K rows, 16 float4 each
    float s[4];
#pragma unroll
    for (int j = 0; j < 4; ++j) {
      float sa = 0.f, sb = 0.f;                // two chains per key
#pragma unroll
      for (int i = 0; i < 8; ++i) {
        float4 u = kr[j * 16 + i];
        float4 w = kr[j * 16 + 8 + i];
        sa = fmaf(q[4 * i],      u.x, sa);
        sa = fmaf(q[4 * i + 1],  u.y, sa);
        sa = fmaf(q[4 * i + 2],  u.z, sa);
        sa = fmaf(q[4 * i + 3],  u.w, sa);
        sb = fmaf(q[32 + 4 * i],     w.x, sb);
        sb = fmaf(q[32 + 4 * i + 1], w.y, sb);
        sb = fmaf(q[32 + 4 * i + 2], w.z, sb);
        sb = fmaf(q[32 + 4 * i + 3], w.w, sb);
      }
      s[j] = sa + sb;
    }
    float mx = fmaxf(fmaxf(s[0], s[1]), fmaxf(s[2], s[3]));
    if (mx > m) {                   // rare after warm-up
      float al = __expf(m - mx);    // first chunk: exp(-1e30)=0
      l *= al;
#pragma unroll
      for (int d = 0; d < 64; ++d) o[d] *= al;
      m = mx;
    }
    float p0 = __expf(s[0] - m);
    float p1 = __expf(s[1] - m);
    float p2 = __expf(s[2] - m);
    float p3 = __expf(s[3] - m);
    l += (p0 + p1) + (p2 + p3);
    const float4* vr = vp + (size_t)k0 * 16;   // 4 V rows
#pragma unroll
    for (int i = 0; i < 16; ++i) {
      float4 u0 = vr[i];
      float4 u1 = vr[16 + i];
      float4 u2 = vr[32 + i];
      float4 u3 = vr[48 + i];
      float a = o[4 * i], b = o[4 * i + 1], c = o[4 * i + 2], d = o[4 * i + 3];
      a = fmaf(p0, u0.x, a); b = fmaf(p0, u0.y, b); c = fmaf(p0, u0.z, c); d = fmaf(p0, u0.w, d);
      a = fmaf(p1, u1.x, a); b = fmaf(p1, u1.y, b); c = fmaf(p1, u1.z, c); d = fmaf(p1, u1.w, d);
      a = fmaf(p2, u2.x, a); b = fmaf(p2, u2.y, b); c = fmaf(p2, u2.z, c); d = fmaf(p2, u2.w, d);
      a = fmaf(p3, u3.x, a); b = fmaf(p3, u3.y, b); c = fmaf(p3, u3.z, c); d = fmaf(p3, u3.w, d);
      o[4 * i] = a; o[4 * i + 1] = b; o[4 * i + 2] = c; o[4 * i + 3] = d;
    }
  }
  float inv = 1.0f / l;
  int b = bh / 12, h = bh - b * 12;
  float* outp = ao + ((size_t)(b * 512 + sq)) * DM + h * 64;
#pragma unroll
  for (int i = 0; i < 16; ++i) {
    float4 t;
    t.x = o[4 * i] * inv; t.y = o[4 * i + 1] * inv;
    t.z = o[4 * i + 2] * inv; t.w = o[4 * i + 3] * inv;
    ((float4*)outp)[i] = t;
  }
}

// ------------------------------------------------------------- bf16 MFMA core
__device__ __forceinline__ void gemm_mainloop(const u16* a0, const u16* a1,
                                              const u16* b0, const u16* b1,
                                              u16* lsA, u16* lsB,
                                              f32x4 acc[4][4], int ksteps) {
  const int tid = threadIdx.x;
  const int lane = tid & 63;
  const int wm = (tid >> 6) & 1, wn = tid >> 7;
  u16* la0 = lsA + tid * 8;
  u16* la1 = lsA + 2048 + tid * 8;
  u16* lb0 = lsB + tid * 8;
  u16* lb1 = lsB + 2048 + tid * 8;
  const u16* ra = lsA + (wm * 64 + (lane & 15)) * 32 + (lane >> 4) * 8;
  const u16* rb = lsB + (wn * 64 + (lane & 15)) * 32 + (lane >> 4) * 8;
  for (int ks = 0; ks < ksteps; ++ks) {
    gld16(a0, la0); gld16(a1, la1);
    gld16(b0, lb0); gld16(b1, lb1);
    a0 += 32; a1 += 32; b0 += 32; b1 += 32;
    __syncthreads();              // drains vmcnt(0): LDS tile complete
    short8 af[4], bfr[4];
#pragma unroll
    for (int i = 0; i < 4; ++i) af[i] = *(const short8*)(ra + i * 512);
#pragma unroll
    for (int j = 0; j < 4; ++j) bfr[j] = *(const short8*)(rb + j * 512);
#pragma unroll
    for (int i = 0; i < 4; ++i)
#pragma unroll
      for (int j = 0; j < 4; ++j)
        acc[i][j] = __builtin_amdgcn_mfma_f32_16x16x32_bf16(af[i], bfr[j], acc[i][j], 0, 0, 0);
    __syncthreads();              // protect LDS before next overwrite
  }
}

#define GEMM_PROLOGUE()                                             \
  const int tid = threadIdx.x;                                      \
  const int r = tid >> 2, c8 = (tid & 3) * 8;                       \
  f32x4 acc[4][4];                                                  \
  {                                                                 \
    f32x4 z = {0.f, 0.f, 0.f, 0.f};                                 \
    _Pragma("unroll") for (int i = 0; i < 4; ++i)                   \
      _Pragma("unroll") for (int j = 0; j < 4; ++j) acc[i][j] = z;  \
  }

#define GEMM_EPI_IDX()                                              \
  const int lane = tid & 63;                                        \
  const int wm = (tid >> 6) & 1, wn = tid >> 7;                     \
  const int ln = lane & 15, q4 = (lane >> 4) * 4;

// ------------------------------------------------------------------- router
// fp32 LN2 recompute + logits. One wave per token; lane 0 picks top-2.
__global__ __launch_bounds__(256) void router_kernel(const float* __restrict__ xres,
    const float* __restrict__ g, const float* __restrict__ bnb,
    const float* __restrict__ Wr, const float* __restrict__ br,
    int* __restrict__ counts, int* __restrict__ idx, float* __restrict__ wgt) {
  const int wv = threadIdx.x >> 6, lane = threadIdx.x & 63;
  const int t = blockIdx.x * 4 + wv;
  const float* row = xres + (size_t)t * DM;
  float xv[12];
  float s = 0.f, s2 = 0.f;
#pragma unroll
  for (int i = 0; i < 12; ++i) {
    float v = row[lane + i * 64];
    xv[i] = v; s += v; s2 += v * v;
  }
#pragma unroll
  for (int off = 32; off > 0; off >>= 1) {
    s += __shfl_xor(s, off, 64);
    s2 += __shfl_xor(s2, off, 64);
  }
  float mean = s * (1.0f / DM);
  float rstd = rsqrtf(s2 * (1.0f / DM) - mean * mean + 1e-5f);
#pragma unroll
  for (int i = 0; i < 12; ++i)
    xv[i] = (xv[i] - mean) * rstd * g[lane + i * 64] + bnb[lane + i * 64];
  float lg[8];
#pragma unroll
  for (int e = 0; e < 8; ++e) {
    float p = 0.f;
#pragma unroll
    for (int i = 0; i < 12; ++i) p = fmaf(xv[i], Wr[e * DM + lane + i * 64], p);
#pragma unroll
    for (int off = 32; off > 0; off >>= 1) p += __shfl_xor(p, off, 64);
    lg[e] = p;
  }
  if (lane == 0) {
    float mx = -1e30f;
#pragma unroll
    for (int e = 0; e < 8; ++e) { lg[e] += br[e]; mx = fmaxf(mx, lg[e]); }
    float ex[8];
#pragma unroll
    for (int e = 0; e < 8; ++e) ex[e] = __expf(lg[e] - mx);
    int e0 = 0;
#pragma unroll
    for (int e = 1; e < 8; ++e) if (ex[e] > ex[e0]) e0 = e;  // ties -> lowest idx
    int e1 = (e0 == 0) ? 1 : 0;
#pragma unroll
    for (int e = 0; e < 8; ++e) if (e != e0 && ex[e] > ex[e1]) e1 = e;
    float denom = 1.0f / (ex[e0] + ex[e1]);
    int s0 = atomicAdd(counts + e0, 1);
    idx[e0 * TOK + s0] = (t << 1);
    wgt[e0 * TOK + s0] = ex[e0] * denom;
    int s1 = atomicAdd(counts + e1, 1);
    idx[e1 * TOK + s1] = (t << 1) | 1;
    wgt[e1 * TOK + s1] = ex[e1] * denom;
  }
}

// exclusive prefix over 8 expert counts (sum is always 32768)
__global__ void offs_kernel(const int* __restrict__ counts, int* __restrict__ offs) {
  if (threadIdx.x == 0) {
    int acc = 0;
    for (int e = 0; e < NEXP; ++e) { offs[e] = acc; acc += counts[e]; }
  }
}

// ------------------------------------------------------------------ MoE GEMMs
__global__ __launch_bounds__(256) void moe_gemm1_kernel(const u16* __restrict__ xm,
    const u16* __restrict__ w1T, const float* __restrict__ b1,
    const int* __restrict__ idx, const int* __restrict__ counts,
    const int* __restrict__ offs, u16* __restrict__ hbuf, int pass) {
  const int e = blockIdx.z;
  const int cnt = counts[e];
  const int gm0 = blockIdx.x * 128;
  if (gm0 >= cnt) return;
  __shared__ __align__(16) u16 lsA[4096];
  __shared__ __align__(16) u16 lsB[4096];
  const int gn0 = blockIdx.y * 128;           // within [0, DH)
  GEMM_PROLOGUE();
  const int s0 = gm0 + r, s1 = gm0 + 64 + r;
  const int t0 = (s0 < cnt) ? (idx[e * TOK + s0] >> 1) : 0;
  const int t1 = (s1 < cnt) ? (idx[e * TOK + s1] >> 1) : 0;
  const u16* a0 = xm + (size_t)t0 * DM + c8;
  const u16* a1 = xm + (size_t)t1 * DM + c8;
  const u16* Be = w1T + (size_t)e * DFF * DM + (size_t)pass * DH * DM;
  const u16* b0 = Be + (size_t)(gn0 + r) * DM + c8;
  const u16* b1p = Be + (size_t)(gn0 + 64 + r) * DM + c8;
  gemm_mainloop(a0, a1, b0, b1p, lsA, lsB, acc, DM / 32);
  GEMM_EPI_IDX();
  const int base = offs[e];
#pragma unroll
  for (int i = 0; i < 4; ++i) {
#pragma unroll
    for (int rr = 0; rr < 4; ++rr) {
      int slot = gm0 + wm * 64 + i * 16 + q4 + rr;
      if (slot >= cnt) continue;
      u16* hrow = hbuf + (size_t)(base + slot) * DH;
#pragma unroll
      for (int j = 0; j < 4; ++j) {
        int n = gn0 + wn * 64 + j * 16 + ln;
        float v = acc[i][j][rr] + b1[e * DFF + pass * DH + n];
        float gg = 0.5f * v * (1.0f + erff(v * 0.70710678118654752f));  // exact gelu
        hrow[n] = f2bf(gg);
      }
    }
  }
}

__global__ __launch_bounds__(256) void moe_gemm2_kernel(const u16* __restrict__ hbuf,
    const u16* __restrict__ w2T, const float* __restrict__ b2,
    const int* __restrict__ idx, const int* __restrict__ counts,
    const int* __restrict__ offs, const float* __restrict__ wgt,
    float* __restrict__ out, int pass) {
  const int e = blockIdx.z;
  const int cnt = counts[e];
  const int gm0 = blockIdx.x * 128;
  if (gm0 >= cnt) return;
  __shared__ __align__(16) u16 lsA[4096];
  __shared__ __align__(16) u16 lsB[4096];
  const int gn0 = blockIdx.y * 128;
  GEMM_PROLOGUE();
  const int base = offs[e];
  int row0 = base + gm0 + r;      if (row0 > ROWS - 1) row0 = ROWS - 1;
  int row1 = base + gm0 + 64 + r; if (row1 > ROWS - 1) row1 = ROWS - 1;
  const u16* a0 = hbuf + (size_t)row0 * DH + c8;
  const u16* a1 = hbuf + (size_t)row1 * DH + c8;
  const u16* Be = w2T + (size_t)e * DM * DFF + (size_t)pass * DH;
  const u16* b0 = Be + (size_t)(gn0 + r) * DFF + c8;
  const u16* b1p = Be + (size_t)(gn0 + 64 + r) * DFF + c8;
  gemm_mainloop(a0, a1, b0, b1p, lsA, lsB, acc, DH / 32);
  GEMM_EPI_IDX();
#pragma unroll
  for (int i = 0; i < 4; ++i) {
#pragma unroll
    for (int rr = 0; rr < 4; ++rr) {
      int slot = gm0 + wm * 64 + i * 16 + q4 + rr;
      if (slot >= cnt) continue;
      int ent = idx[e * TOK + slot];
      int t = ent >> 1;
      float wv = wgt[e * TOK + slot];
#pragma unroll
      for (int j = 0; j < 4; ++j) {
        int n = gn0 + wn * 64 + j * 16 + ln;
        float bb = pass ? 0.f : b2[e * DM + n];   // bias once (pass 0)
        atomicAdd(out + (size_t)t * DM + n, wv * (acc[i][j][rr] + bb));
      }
    }
  }
}

// -------------------------------------------------------------------- launch
extern "C" void kernel_launch(void* const* d_in, const int* in_sizes, int n_in,
                              void* d_out, int out_size, void* d_ws, size_t ws_size,
                              hipStream_t stream) {
  const float* x     = (const float*)d_in[0];
  const float* ln1_g = (const float*)d_in[1];
  const float* ln1_b = (const float*)d_in[2];
  const float* in_w  = (const float*)d_in[3];
  const float* in_b  = (const float*)d_in[4];
  const float* out_w = (const float*)d_in[5];
  const float* out_b = (const float*)d_in[6];
  const float* ln2_g = (const float*)d_in[7];
  const float* ln2_b = (const float*)d_in[8];
  const float* rtr_w = (const float*)d_in[9];
  const float* rtr_b = (const float*)d_in[10];
  const float* w1    = (const float*)d_in[11];
  const float* b1    = (const float*)d_in[12];
  const float* w2    = (const float*)d_in[13];
  const float* b2    = (const float*)d_in[14];
  float* xres = (float*)d_out;                       // residual lives in d_out

  char* p = (char*)d_ws;
  auto take = [&](size_t bytes) { char* r = p; p += (bytes + 255) & ~(size_t)255; return r; };
  int* idx    = (int*)take((size_t)NEXP * TOK * 4);       // 0.5 MB
  float* wgt  = (float*)take((size_t)NEXP * TOK * 4);     // 0.5 MB
  int* counts = (int*)take(64);
  int* offs   = (int*)take(64);
  char* arena = take((size_t)4 * TOK * DM * 4);           // 201.3 MB, phase-aliased
  // phase A (attention, all fp32):
  float* x2f = (float*)(arena);                            // 50.3 MB (LN1 out; later aof)
  float* qf  = (float*)(arena + (size_t)1 * TOK * DM * 4);
  float* kf  = (float*)(arena + (size_t)2 * TOK * DM * 4);
  float* vf  = (float*)(arena + (size_t)3 * TOK * DM * 4);
  float* aof = x2f;                                        // x2f dead after qkv
  // phase B (MoE, after outproj; overlays phase A exactly):
  u16* w1T  = (u16*)(arena);                               // 37.7 MB [E][Dff][D]
  u16* w2T  = (u16*)(arena + (size_t)NEXP * DFF * DM * 2); // 37.7 MB [E][D][Dff]
  u16* xm   = (u16*)(arena + (size_t)2 * NEXP * DFF * DM * 2);          // 25.2 MB
  u16* hbuf = (u16*)(arena + (size_t)2 * NEXP * DFF * DM * 2 + (size_t)TOK * DM * 2); // 100.7 MB
  // total ws use: ~202.4 MB

  hipMemsetAsync(counts, 0, 32, stream);

  // ---- attention path, fully fp32 (router decisions must match fp32 ref) ----
  ln_f32_kernel<<<TOK, 256, 0, stream>>>(x, ln1_g, ln1_b, x2f);
  qkv_f32_kernel<<<dim3(TOK / 256, 3 * DM / 128), 256, 0, stream>>>(x2f, in_w, in_b, qf, kf, vf);
  attn_f32_kernel<<<32 * 12 * 2, 256, 0, stream>>>(qf, kf, vf, aof);
  outproj_f32_kernel<<<dim3(TOK / 256, DM / 128), 256, 0, stream>>>(aof, out_w, out_b, x, xres);

  // ---- MoE path, bf16 MFMA (post-router noise is within threshold) ----
  transpose_cast_kernel<<<dim3(DFF / 32, DM / 32, NEXP), dim3(32, 8), 0, stream>>>(w1, w1T, DM, DFF);
  transpose_cast_kernel<<<dim3(DM / 32, DFF / 32, NEXP), dim3(32, 8), 0, stream>>>(w2, w2T, DFF, DM);
  ln_bf16_kernel<<<TOK, 256, 0, stream>>>(xres, ln2_g, ln2_b, xm);
  router_kernel<<<TOK / 4, 256, 0, stream>>>(xres, ln2_g, ln2_b, rtr_w, rtr_b, counts, idx, wgt);
  offs_kernel<<<1, 64, 0, stream>>>(counts, offs);

  for (int pass = 0; pass < 2; ++pass) {
    moe_gemm1_kernel<<<dim3(TOK / 128, DH / 128, NEXP), 256, 0, stream>>>(
        xm, w1T, b1, idx, counts, offs, hbuf, pass);
    moe_gemm2_kernel<<<dim3(TOK / 128, DM / 128, NEXP), 256, 0, stream>>>(
        hbuf, w2T, b2, idx, counts, offs, wgt, xres, pass);
  }
}

// Round 4
// 2921.838 us; speedup vs baseline: 1.0243x; 1.0243x over previous
//
#include <hip/hip_runtime.h>

typedef unsigned short u16;
typedef unsigned int   u32;
typedef __attribute__((ext_vector_type(8))) short short8;
typedef __attribute__((ext_vector_type(4))) float f32x4;

#define AS1 __attribute__((address_space(1)))
#define AS3 __attribute__((address_space(3)))

#define TOK   16384
#define DM    768
#define DFF   3072
#define DH    1536          // Dff half (two-pass MoE)
#define NEXP  8
#define ROWS  32768         // total routed rows = 2*TOK exactly

static __device__ __forceinline__ void gld16(const void* g, void* l) {
  __builtin_amdgcn_global_load_lds((const AS1 void*)g, (AS3 void*)l, 16, 0, 0);
}
static __device__ __forceinline__ u16 f2bf(float f) {
  u32 u = __float_as_uint(f);
  return (u16)((u + 0x7fffu + ((u >> 16) & 1u)) >> 16);  // RNE
}

// ---------------------------------------------------------------- small utils
// in: [z][R][C] fp32  ->  out: [z][C][R] bf16
__global__ __launch_bounds__(256) void transpose_cast_kernel(const float* __restrict__ in,
                                                             u16* __restrict__ out, int R, int C) {
  __shared__ float tile[32][33];
  const float* src = in + (size_t)blockIdx.z * R * C;
  u16* dst = out + (size_t)blockIdx.z * R * C;
  int tx = threadIdx.x, ty = threadIdx.y;
#pragma unroll
  for (int yy = 0; yy < 4; ++yy) {
    int r = blockIdx.y * 32 + ty + yy * 8;
    int c = blockIdx.x * 32 + tx;
    tile[ty + yy * 8][tx] = src[(size_t)r * C + c];
  }
  __syncthreads();
#pragma unroll
  for (int yy = 0; yy < 4; ++yy) {
    int oc = blockIdx.x * 32 + ty + yy * 8;   // output row (= input col)
    dst[(size_t)oc * R + blockIdx.y * 32 + tx] = f2bf(tile[tx][ty + yy * 8]);
  }
}

// LayerNorm over D=768, fp32 math. One block per token. Two output variants.
__global__ __launch_bounds__(256) void ln_f32_kernel(const float* __restrict__ x,
    const float* __restrict__ g, const float* __restrict__ b, float* __restrict__ out) {
  const int t = blockIdx.x;
  const int tid = threadIdx.x;
  const float* row = x + (size_t)t * DM;
  float v0 = row[tid], v1 = row[tid + 256], v2 = row[tid + 512];
  float s = v0 + v1 + v2;
  float s2 = v0 * v0 + v1 * v1 + v2 * v2;
#pragma unroll
  for (int off = 32; off > 0; off >>= 1) {
    s += __shfl_down(s, off, 64);
    s2 += __shfl_down(s2, off, 64);
  }
  __shared__ float red[8];
  if ((tid & 63) == 0) { red[tid >> 6] = s; red[4 + (tid >> 6)] = s2; }
  __syncthreads();
  float S = red[0] + red[1] + red[2] + red[3];
  float S2 = red[4] + red[5] + red[6] + red[7];
  float mean = S * (1.0f / DM);
  float var = S2 * (1.0f / DM) - mean * mean;
  float rstd = rsqrtf(var + 1e-5f);
  float* orow = out + (size_t)t * DM;
  orow[tid]       = (v0 - mean) * rstd * g[tid]       + b[tid];
  orow[tid + 256] = (v1 - mean) * rstd * g[tid + 256] + b[tid + 256];
  orow[tid + 512] = (v2 - mean) * rstd * g[tid + 512] + b[tid + 512];
}

__global__ __launch_bounds__(256) void ln_bf16_kernel(const float* __restrict__ x,
    const float* __restrict__ g, const float* __restrict__ b, u16* __restrict__ out) {
  const int t = blockIdx.x;
  const int tid = threadIdx.x;
  const float* row = x + (size_t)t * DM;
  float v0 = row[tid], v1 = row[tid + 256], v2 = row[tid + 512];
  float s = v0 + v1 + v2;
  float s2 = v0 * v0 + v1 * v1 + v2 * v2;
#pragma unroll
  for (int off = 32; off > 0; off >>= 1) {
    s += __shfl_down(s, off, 64);
    s2 += __shfl_down(s2, off, 64);
  }
  __shared__ float red[8];
  if ((tid & 63) == 0) { red[tid >> 6] = s; red[4 + (tid >> 6)] = s2; }
  __syncthreads();
  float S = red[0] + red[1] + red[2] + red[3];
  float S2 = red[4] + red[5] + red[6] + red[7];
  float mean = S * (1.0f / DM);
  float var = S2 * (1.0f / DM) - mean * mean;
  float rstd = rsqrtf(var + 1e-5f);
  u16* orow = out + (size_t)t * DM;
  orow[tid]       = f2bf((v0 - mean) * rstd * g[tid]       + b[tid]);
  orow[tid + 256] = f2bf((v1 - mean) * rstd * g[tid + 256] + b[tid + 256]);
  orow[tid + 512] = f2bf((v2 - mean) * rstd * g[tid + 512] + b[tid + 512]);
}

// -------------------------------------------------------- fp32 GEMM mainloop
// C[128x128] = A[M][K] * B[N][K]^T, all fp32. 256 threads, 8x8 per thread.
// BK=16. lsA/lsB are [16][128] fp32 staged transposed (k-major).
// Fragments: rows = tm*8 + ii (8 consecutive, broadcast across wave);
// cols = (jj>>2)*64 + tn*4 + (jj&3): two float4 groups -> 2-way bank alias
// max (free, m136). This removes the 4-way conflict of the tn*8 layout.
__device__ __forceinline__ void sgemm_mainloop(const float* __restrict__ A,
    const float* __restrict__ B, int lda, int ldb, int gm0, int gn0, int K,
    float (*lsA)[128], float (*lsB)[128], float acc[8][8]) {
  const int tid = threadIdx.x;
  const int srow = tid >> 1;          // 0..127
  const int skoff = (tid & 1) * 8;    // 0 or 8
  const int tm = tid >> 4, tn = tid & 15;
  const float* ga = A + (size_t)(gm0 + srow) * lda + skoff;
  const float* gb = B + (size_t)(gn0 + srow) * ldb + skoff;
  for (int k0 = 0; k0 < K; k0 += 16) {
    float4 a0 = *(const float4*)(ga);
    float4 a1 = *(const float4*)(ga + 4);
    float4 b0 = *(const float4*)(gb);
    float4 b1 = *(const float4*)(gb + 4);
    ga += 16; gb += 16;
    __syncthreads();   // previous compute done before overwrite
    lsA[skoff + 0][srow] = a0.x; lsA[skoff + 1][srow] = a0.y;
    lsA[skoff + 2][srow] = a0.z; lsA[skoff + 3][srow] = a0.w;
    lsA[skoff + 4][srow] = a1.x; lsA[skoff + 5][srow] = a1.y;
    lsA[skoff + 6][srow] = a1.z; lsA[skoff + 7][srow] = a1.w;
    lsB[skoff + 0][srow] = b0.x; lsB[skoff + 1][srow] = b0.y;
    lsB[skoff + 2][srow] = b0.z; lsB[skoff + 3][srow] = b0.w;
    lsB[skoff + 4][srow] = b1.x; lsB[skoff + 5][srow] = b1.y;
    lsB[skoff + 6][srow] = b1.z; lsB[skoff + 7][srow] = b1.w;
    __syncthreads();
#pragma unroll
    for (int k = 0; k < 16; ++k) {
      float4 av0 = *(const float4*)&lsA[k][tm * 8];
      float4 av1 = *(const float4*)&lsA[k][tm * 8 + 4];
      float4 bv0 = *(const float4*)&lsB[k][tn * 4];
      float4 bv1 = *(const float4*)&lsB[k][64 + tn * 4];
      float av[8] = {av0.x, av0.y, av0.z, av0.w, av1.x, av1.y, av1.z, av1.w};
      float bv[8] = {bv0.x, bv0.y, bv0.z, bv0.w, bv1.x, bv1.y, bv1.z, bv1.w};
#pragma unroll
      for (int i = 0; i < 8; ++i)
#pragma unroll
        for (int j = 0; j < 8; ++j)
          acc[i][j] = fmaf(av[i], bv[j], acc[i][j]);
    }
  }
}

// QKV fp32: A=x2f[T][768], B=in_proj_w[2304][768]; scatter to q/k/v [B,H,S,64] fp32
__global__ __launch_bounds__(256) void qkv_f32_kernel(const float* __restrict__ A,
    const float* __restrict__ Bw, const float* __restrict__ bias,
    float* __restrict__ qf, float* __restrict__ kf, float* __restrict__ vf) {
  __shared__ float lsA[16][128];
  __shared__ float lsB[16][128];
  const int gm0 = blockIdx.x * 128, gn0 = blockIdx.y * 128;
  float acc[8][8];
#pragma unroll
  for (int i = 0; i < 8; ++i)
#pragma unroll
    for (int j = 0; j < 8; ++j) acc[i][j] = 0.f;
  sgemm_mainloop(A, Bw, DM, DM, gm0, gn0, DM, lsA, lsB, acc);
  const int tm = threadIdx.x >> 4, tn = threadIdx.x & 15;
#pragma unroll
  for (int jj = 0; jj < 8; ++jj) {
    int col = gn0 + (jj >> 2) * 64 + tn * 4 + (jj & 3);
    int which = col / DM;
    int rem = col - which * DM;
    int hh = rem >> 6, dd = rem & 63;
    float bc = bias[col];
    float* dst = which == 0 ? qf : (which == 1 ? kf : vf);
#pragma unroll
    for (int ii = 0; ii < 8; ++ii) {
      int t = gm0 + tm * 8 + ii;
      int bb = t >> 9, ss = t & 511;
      dst[(((size_t)(bb * 12 + hh) * 512 + ss) << 6) + dd] = acc[ii][jj] + bc;
    }
  }
}

// Out-proj fp32: A=aof[T][768], B=out_proj_w[768][768]; + bias + residual -> xres
__global__ __launch_bounds__(256) void outproj_f32_kernel(const float* __restrict__ A,
    const float* __restrict__ Bw, const float* __restrict__ bias,
    const float* __restrict__ xin, float* __restrict__ xres) {
  __shared__ float lsA[16][128];
  __shared__ float lsB[16][128];
  const int gm0 = blockIdx.x * 128, gn0 = blockIdx.y * 128;
  float acc[8][8];
#pragma unroll
  for (int i = 0; i < 8; ++i)
#pragma unroll
    for (int j = 0; j < 8; ++j) acc[i][j] = 0.f;
  sgemm_mainloop(A, Bw, DM, DM, gm0, gn0, DM, lsA, lsB, acc);
  const int tm = threadIdx.x >> 4, tn = threadIdx.x & 15;
#pragma unroll
  for (int ii = 0; ii < 8; ++ii) {
    int t = gm0 + tm * 8 + ii;
#pragma unroll
    for (int jj = 0; jj < 8; ++jj) {
      int n = gn0 + (jj >> 2) * 64 + tn * 4 + (jj & 3);
      size_t off = (size_t)t * DM + n;
      xres[off] = acc[ii][jj] + bias[n] + xin[off];
    }
  }
}

// ------------------------------------------------------------ fp32 attention
// One thread per query row. No cross-lane ops. Keys processed in chunks of 4:
// 8 independent dot chains (2 half-dots x 4 keys), one max/rescale per chunk
// (record-breaking chunks are rare: ~ln(128) of 128), 64 independent PV
// accumulator chains. q[64]+o[64] kept in VGPRs via __launch_bounds__(256,2).
__global__ __launch_bounds__(256, 2) void attn_f32_kernel(const float* __restrict__ qb,
    const float* __restrict__ kb, const float* __restrict__ vb, float* __restrict__ ao) {
  const int bh = blockIdx.x >> 1;
  const int sq = (blockIdx.x & 1) * 256 + threadIdx.x;
  const size_t base = (size_t)bh * 512 * 64;
  const float* qp = qb + base + (size_t)sq * 64;
  float q[64];
#pragma unroll
  for (int i = 0; i < 16; ++i) {
    float4 t = ((const float4*)qp)[i];
    q[4 * i]     = t.x * 0.125f;   // fold 1/sqrt(64)
    q[4 * i + 1] = t.y * 0.125f;
    q[4 * i + 2] = t.z * 0.125f;
    q[4 * i + 3] = t.w * 0.125f;
  }
  float m = -1e30f, l = 0.f, o[64];
#pragma unroll
  for (int d = 0; d < 64; ++d) o[d] = 0.f;
  const float4* kp = (const float4*)(kb + base);
  const float4* vp = (const float4*)(vb + base);
  for (int k0 = 0; k0 < 512; k0 += 4) {
    const float4* kr = kp + (size_t)k0 * 16;   // 4 K rows, 16 float4 each
    float s[4];
#pragma unroll
    for (int j = 0; j < 4; ++j) {
      float sa = 0.f, sb = 0.f;                // two chains per key
#pragma unroll
      for (int i = 0; i < 8; ++i) {
        float4 u = kr[j * 16 + i];
        float4 w = kr[j * 16 + 8 + i];
        sa = fmaf(q[4 * i],      u.x, sa);
        sa = fmaf(q[4 * i + 1],  u.y, sa);
        sa = fmaf(q[4 * i + 2],  u.z, sa);
        sa = fmaf(q[4 * i + 3],  u.w, sa);
        sb = fmaf(q[32 + 4 * i],     w.x, sb);
        sb = fmaf(q[32 + 4 * i + 1], w.y, sb);
        sb = fmaf(q[32 + 4 * i + 2], w.z, sb);
        sb = fmaf(q[32 + 4 * i + 3], w.w, sb);
      }
      s[j] = sa + sb;
    }
    float mx = fmaxf(fmaxf(s[0], s[1]), fmaxf(s[2], s[3]));
    if (mx > m) {                   // rare after warm-up
      float al = __expf(m - mx);    // first chunk: exp(-1e30)=0
      l *= al;
#pragma unroll
      for (int d = 0; d < 64; ++d) o[d] *= al;
      m = mx;
    }
    float p0 = __expf(s[0] - m);
    float p1 = __expf(s[1] - m);
    float p2 = __expf(s[2] - m);
    float p3 = __expf(s[3] - m);
    l += (p0 + p1) + (p2 + p3);
    const float4* vr = vp + (size_t)k0 * 16;   // 4 V rows
#pragma unroll
    for (int i = 0; i < 16; ++i) {
      float4 u0 = vr[i];
      float4 u1 = vr[16 + i];
      float4 u2 = vr[32 + i];
      float4 u3 = vr[48 + i];
      float a = o[4 * i], b = o[4 * i + 1], c = o[4 * i + 2], d = o[4 * i + 3];
      a = fmaf(p0, u0.x, a); b = fmaf(p0, u0.y, b); c = fmaf(p0, u0.z, c); d = fmaf(p0, u0.w, d);
      a = fmaf(p1, u1.x, a); b = fmaf(p1, u1.y, b); c = fmaf(p1, u1.z, c); d = fmaf(p1, u1.w, d);
      a = fmaf(p2, u2.x, a); b = fmaf(p2, u2.y, b); c = fmaf(p2, u2.z, c); d = fmaf(p2, u2.w, d);
      a = fmaf(p3, u3.x, a); b = fmaf(p3, u3.y, b); c = fmaf(p3, u3.z, c); d = fmaf(p3, u3.w, d);
      o[4 * i] = a; o[4 * i + 1] = b; o[4 * i + 2] = c; o[4 * i + 3] = d;
    }
  }
  float inv = 1.0f / l;
  int b = bh / 12, h = bh - b * 12;
  float* outp = ao + ((size_t)(b * 512 + sq)) * DM + h * 64;
#pragma unroll
  for (int i = 0; i < 16; ++i) {
    float4 t;
    t.x = o[4 * i] * inv; t.y = o[4 * i + 1] * inv;
    t.z = o[4 * i + 2] * inv; t.w = o[4 * i + 3] * inv;
    ((float4*)outp)[i] = t;
  }
}

// ------------------------------------------------------------- bf16 MFMA core
__device__ __forceinline__ void gemm_mainloop(const u16* a0, const u16* a1,
                                              const u16* b0, const u16* b1,
                                              u16* lsA, u16* lsB,
                                              f32x4 acc[4][4], int ksteps) {
  const int tid = threadIdx.x;
  const int lane = tid & 63;
  const int wm = (tid >> 6) & 1, wn = tid >> 7;
  u16* la0 = lsA + tid * 8;
  u16* la1 = lsA + 2048 + tid * 8;
  u16* lb0 = lsB + tid * 8;
  u16* lb1 = lsB + 2048 + tid * 8;
  const u16* ra = lsA + (wm * 64 + (lane & 15)) * 32 + (lane >> 4) * 8;
  const u16* rb = lsB + (wn * 64 + (lane & 15)) * 32 + (lane >> 4) * 8;
  for (int ks = 0; ks < ksteps; ++ks) {
    gld16(a0, la0); gld16(a1, la1);
    gld16(b0, lb0); gld16(b1, lb1);
    a0 += 32; a1 += 32; b0 += 32; b1 += 32;
    __syncthreads();              // drains vmcnt(0): LDS tile complete
    short8 af[4], bfr[4];
#pragma unroll
    for (int i = 0; i < 4; ++i) af[i] = *(const short8*)(ra + i * 512);
#pragma unroll
    for (int j = 0; j < 4; ++j) bfr[j] = *(const short8*)(rb + j * 512);
#pragma unroll
    for (int i = 0; i < 4; ++i)
#pragma unroll
      for (int j = 0; j < 4; ++j)
        acc[i][j] = __builtin_amdgcn_mfma_f32_16x16x32_bf16(af[i], bfr[j], acc[i][j], 0, 0, 0);
    __syncthreads();              // protect LDS before next overwrite
  }
}

#define GEMM_PROLOGUE()                                             \
  const int tid = threadIdx.x;                                      \
  const int r = tid >> 2, c8 = (tid & 3) * 8;                       \
  f32x4 acc[4][4];                                                  \
  {                                                                 \
    f32x4 z = {0.f, 0.f, 0.f, 0.f};                                 \
    _Pragma("unroll") for (int i = 0; i < 4; ++i)                   \
      _Pragma("unroll") for (int j = 0; j < 4; ++j) acc[i][j] = z;  \
  }

#define GEMM_EPI_IDX()                                              \
  const int lane = tid & 63;                                        \
  const int wm = (tid >> 6) & 1, wn = tid >> 7;                     \
  const int ln = lane & 15, q4 = (lane >> 4) * 4;

// ------------------------------------------------------------------- router
// fp32 LN2 recompute + logits. One wave per token; lane 0 picks top-2.
__global__ __launch_bounds__(256) void router_kernel(const float* __restrict__ xres,
    const float* __restrict__ g, const float* __restrict__ bnb,
    const float* __restrict__ Wr, const float* __restrict__ br,
    int* __restrict__ counts, int* __restrict__ idx, float* __restrict__ wgt) {
  const int wv = threadIdx.x >> 6, lane = threadIdx.x & 63;
  const int t = blockIdx.x * 4 + wv;
  const float* row = xres + (size_t)t * DM;
  float xv[12];
  float s = 0.f, s2 = 0.f;
#pragma unroll
  for (int i = 0; i < 12; ++i) {
    float v = row[lane + i * 64];
    xv[i] = v; s += v; s2 += v * v;
  }
#pragma unroll
  for (int off = 32; off > 0; off >>= 1) {
    s += __shfl_xor(s, off, 64);
    s2 += __shfl_xor(s2, off, 64);
  }
  float mean = s * (1.0f / DM);
  float rstd = rsqrtf(s2 * (1.0f / DM) - mean * mean + 1e-5f);
#pragma unroll
  for (int i = 0; i < 12; ++i)
    xv[i] = (xv[i] - mean) * rstd * g[lane + i * 64] + bnb[lane + i * 64];
  float lg[8];
#pragma unroll
  for (int e = 0; e < 8; ++e) {
    float p = 0.f;
#pragma unroll
    for (int i = 0; i < 12; ++i) p = fmaf(xv[i], Wr[e * DM + lane + i * 64], p);
#pragma unroll
    for (int off = 32; off > 0; off >>= 1) p += __shfl_xor(p, off, 64);
    lg[e] = p;
  }
  if (lane == 0) {
    float mx = -1e30f;
#pragma unroll
    for (int e = 0; e < 8; ++e) { lg[e] += br[e]; mx = fmaxf(mx, lg[e]); }
    float ex[8];
#pragma unroll
    for (int e = 0; e < 8; ++e) ex[e] = __expf(lg[e] - mx);
    int e0 = 0;
#pragma unroll
    for (int e = 1; e < 8; ++e) if (ex[e] > ex[e0]) e0 = e;  // ties -> lowest idx
    int e1 = (e0 == 0) ? 1 : 0;
#pragma unroll
    for (int e = 0; e < 8; ++e) if (e != e0 && ex[e] > ex[e1]) e1 = e;
    float denom = 1.0f / (ex[e0] + ex[e1]);
    int s0 = atomicAdd(counts + e0, 1);
    idx[e0 * TOK + s0] = (t << 1);
    wgt[e0 * TOK + s0] = ex[e0] * denom;
    int s1 = atomicAdd(counts + e1, 1);
    idx[e1 * TOK + s1] = (t << 1) | 1;
    wgt[e1 * TOK + s1] = ex[e1] * denom;
  }
}

// exclusive prefix over 8 expert counts (sum is always 32768)
__global__ void offs_kernel(const int* __restrict__ counts, int* __restrict__ offs) {
  if (threadIdx.x == 0) {
    int acc = 0;
    for (int e = 0; e < NEXP; ++e) { offs[e] = acc; acc += counts[e]; }
  }
}

// ------------------------------------------------------------------ MoE GEMMs
__global__ __launch_bounds__(256) void moe_gemm1_kernel(const u16* __restrict__ xm,
    const u16* __restrict__ w1T, const float* __restrict__ b1,
    const int* __restrict__ idx, const int* __restrict__ counts,
    const int* __restrict__ offs, u16* __restrict__ hbuf, int pass) {
  const int e = blockIdx.z;
  const int cnt = counts[e];
  const int gm0 = blockIdx.x * 128;
  if (gm0 >= cnt) return;
  __shared__ __align__(16) u16 lsA[4096];
  __shared__ __align__(16) u16 lsB[4096];
  const int gn0 = blockIdx.y * 128;           // within [0, DH)
  GEMM_PROLOGUE();
  const int s0 = gm0 + r, s1 = gm0 + 64 + r;
  const int t0 = (s0 < cnt) ? (idx[e * TOK + s0] >> 1) : 0;
  const int t1 = (s1 < cnt) ? (idx[e * TOK + s1] >> 1) : 0;
  const u16* a0 = xm + (size_t)t0 * DM + c8;
  const u16* a1 = xm + (size_t)t1 * DM + c8;
  const u16* Be = w1T + (size_t)e * DFF * DM + (size_t)pass * DH * DM;
  const u16* b0 = Be + (size_t)(gn0 + r) * DM + c8;
  const u16* b1p = Be + (size_t)(gn0 + 64 + r) * DM + c8;
  gemm_mainloop(a0, a1, b0, b1p, lsA, lsB, acc, DM / 32);
  GEMM_EPI_IDX();
  const int base = offs[e];
#pragma unroll
  for (int i = 0; i < 4; ++i) {
#pragma unroll
    for (int rr = 0; rr < 4; ++rr) {
      int slot = gm0 + wm * 64 + i * 16 + q4 + rr;
      if (slot >= cnt) continue;
      u16* hrow = hbuf + (size_t)(base + slot) * DH;
#pragma unroll
      for (int j = 0; j < 4; ++j) {
        int n = gn0 + wn * 64 + j * 16 + ln;
        float v = acc[i][j][rr] + b1[e * DFF + pass * DH + n];
        float gg = 0.5f * v * (1.0f + erff(v * 0.70710678118654752f));  // exact gelu
        hrow[n] = f2bf(gg);
      }
    }
  }
}

__global__ __launch_bounds__(256) void moe_gemm2_kernel(const u16* __restrict__ hbuf,
    const u16* __restrict__ w2T, const float* __restrict__ b2,
    const int* __restrict__ idx, const int* __restrict__ counts,
    const int* __restrict__ offs, const float* __restrict__ wgt,
    float* __restrict__ out, int pass) {
  const int e = blockIdx.z;
  const int cnt = counts[e];
  const int gm0 = blockIdx.x * 128;
  if (gm0 >= cnt) return;
  __shared__ __align__(16) u16 lsA[4096];
  __shared__ __align__(16) u16 lsB[4096];
  const int gn0 = blockIdx.y * 128;
  GEMM_PROLOGUE();
  const int base = offs[e];
  int row0 = base + gm0 + r;      if (row0 > ROWS - 1) row0 = ROWS - 1;
  int row1 = base + gm0 + 64 + r; if (row1 > ROWS - 1) row1 = ROWS - 1;
  const u16* a0 = hbuf + (size_t)row0 * DH + c8;
  const u16* a1 = hbuf + (size_t)row1 * DH + c8;
  const u16* Be = w2T + (size_t)e * DM * DFF + (size_t)pass * DH;
  const u16* b0 = Be + (size_t)(gn0 + r) * DFF + c8;
  const u16* b1p = Be + (size_t)(gn0 + 64 + r) * DFF + c8;
  gemm_mainloop(a0, a1, b0, b1p, lsA, lsB, acc, DH / 32);
  GEMM_EPI_IDX();
#pragma unroll
  for (int i = 0; i < 4; ++i) {
#pragma unroll
    for (int rr = 0; rr < 4; ++rr) {
      int slot = gm0 + wm * 64 + i * 16 + q4 + rr;
      if (slot >= cnt) continue;
      int ent = idx[e * TOK + slot];
      int t = ent >> 1;
      float wv = wgt[e * TOK + slot];
#pragma unroll
      for (int j = 0; j < 4; ++j) {
        int n = gn0 + wn * 64 + j * 16 + ln;
        float bb = pass ? 0.f : b2[e * DM + n];   // bias once (pass 0)
        atomicAdd(out + (size_t)t * DM + n, wv * (acc[i][j][rr] + bb));
      }
    }
  }
}

// -------------------------------------------------------------------- launch
extern "C" void kernel_launch(void* const* d_in, const int* in_sizes, int n_in,
                              void* d_out, int out_size, void* d_ws, size_t ws_size,
                              hipStream_t stream) {
  const float* x     = (const float*)d_in[0];
  const float* ln1_g = (const float*)d_in[1];
  const float* ln1_b = (const float*)d_in[2];
  const float* in_w  = (const float*)d_in[3];
  const float* in_b  = (const float*)d_in[4];
  const float* out_w = (const float*)d_in[5];
  const float* out_b = (const float*)d_in[6];
  const float* ln2_g = (const float*)d_in[7];
  const float* ln2_b = (const float*)d_in[8];
  const float* rtr_w = (const float*)d_in[9];
  const float* rtr_b = (const float*)d_in[10];
  const float* w1    = (const float*)d_in[11];
  const float* b1    = (const float*)d_in[12];
  const float* w2    = (const float*)d_in[13];
  const float* b2    = (const float*)d_in[14];
  float* xres = (float*)d_out;                       // residual lives in d_out

  char* p = (char*)d_ws;
  auto take = [&](size_t bytes) { char* r = p; p += (bytes + 255) & ~(size_t)255; return r; };
  int* idx    = (int*)take((size_t)NEXP * TOK * 4);       // 0.5 MB
  float* wgt  = (float*)take((size_t)NEXP * TOK * 4);     // 0.5 MB
  int* counts = (int*)take(64);
  int* offs   = (int*)take(64);
  char* arena = take((size_t)4 * TOK * DM * 4);           // 201.3 MB, phase-aliased
  // phase A (attention, all fp32):
  float* x2f = (float*)(arena);                            // 50.3 MB (LN1 out; later aof)
  float* qf  = (float*)(arena + (size_t)1 * TOK * DM * 4);
  float* kf  = (float*)(arena + (size_t)2 * TOK * DM * 4);
  float* vf  = (float*)(arena + (size_t)3 * TOK * DM * 4);
  float* aof = x2f;                                        // x2f dead after qkv
  // phase B (MoE, after outproj; overlays phase A exactly):
  u16* w1T  = (u16*)(arena);                               // 37.7 MB [E][Dff][D]
  u16* w2T  = (u16*)(arena + (size_t)NEXP * DFF * DM * 2); // 37.7 MB [E][D][Dff]
  u16* xm   = (u16*)(arena + (size_t)2 * NEXP * DFF * DM * 2);          // 25.2 MB
  u16* hbuf = (u16*)(arena + (size_t)2 * NEXP * DFF * DM * 2 + (size_t)TOK * DM * 2); // 100.7 MB
  // total ws use: ~202.4 MB

  hipMemsetAsync(counts, 0, 32, stream);

  // ---- attention path, fully fp32 (router decisions must match fp32 ref) ----
  ln_f32_kernel<<<TOK, 256, 0, stream>>>(x, ln1_g, ln1_b, x2f);
  qkv_f32_kernel<<<dim3(TOK / 128, 3 * DM / 128), 256, 0, stream>>>(x2f, in_w, in_b, qf, kf, vf);
  attn_f32_kernel<<<32 * 12 * 2, 256, 0, stream>>>(qf, kf, vf, aof);
  outproj_f32_kernel<<<dim3(TOK / 128, DM / 128), 256, 0, stream>>>(aof, out_w, out_b, x, xres);

  // ---- MoE path, bf16 MFMA (post-router noise is within threshold) ----
  transpose_cast_kernel<<<dim3(DFF / 32, DM / 32, NEXP), dim3(32, 8), 0, stream>>>(w1, w1T, DM, DFF);
  transpose_cast_kernel<<<dim3(DM / 32, DFF / 32, NEXP), dim3(32, 8), 0, stream>>>(w2, w2T, DFF, DM);
  ln_bf16_kernel<<<TOK, 256, 0, stream>>>(xres, ln2_g, ln2_b, xm);
  router_kernel<<<TOK / 4, 256, 0, stream>>>(xres, ln2_g, ln2_b, rtr_w, rtr_b, counts, idx, wgt);
  offs_kernel<<<1, 64, 0, stream>>>(counts, offs);

  for (int pass = 0; pass < 2; ++pass) {
    moe_gemm1_kernel<<<dim3(TOK / 128, DH / 128, NEXP), 256, 0, stream>>>(
        xm, w1T, b1, idx, counts, offs, hbuf, pass);
    moe_gemm2_kernel<<<dim3(TOK / 128, DM / 128, NEXP), 256, 0, stream>>>(
        hbuf, w2T, b2, idx, counts, offs, wgt, xres, pass);
  }
}

// Round 5
// 2889.479 us; speedup vs baseline: 1.0357x; 1.0112x over previous
//
#include <hip/hip_runtime.h>

typedef unsigned short u16;
typedef unsigned int   u32;
typedef __attribute__((ext_vector_type(8))) short short8;
typedef __attribute__((ext_vector_type(4))) float f32x4;

#define AS1 __attribute__((address_space(1)))
#define AS3 __attribute__((address_space(3)))

#define TOK   16384
#define DM    768
#define DFF   3072
#define DH    1536          // Dff half (two-pass MoE)
#define NEXP  8
#define ROWS  32768         // total routed rows = 2*TOK exactly

static __device__ __forceinline__ void gld16(const void* g, void* l) {
  __builtin_amdgcn_global_load_lds((const AS1 void*)g, (AS3 void*)l, 16, 0, 0);
}
static __device__ __forceinline__ u16 f2bf(float f) {
  u32 u = __float_as_uint(f);
  return (u16)((u + 0x7fffu + ((u >> 16) & 1u)) >> 16);  // RNE
}

// ---------------------------------------------------------------- small utils
// in: [z][R][C] fp32  ->  out: [z][C][R] bf16
__global__ __launch_bounds__(256) void transpose_cast_kernel(const float* __restrict__ in,
                                                             u16* __restrict__ out, int R, int C) {
  __shared__ float tile[32][33];
  const float* src = in + (size_t)blockIdx.z * R * C;
  u16* dst = out + (size_t)blockIdx.z * R * C;
  int tx = threadIdx.x, ty = threadIdx.y;
#pragma unroll
  for (int yy = 0; yy < 4; ++yy) {
    int r = blockIdx.y * 32 + ty + yy * 8;
    int c = blockIdx.x * 32 + tx;
    tile[ty + yy * 8][tx] = src[(size_t)r * C + c];
  }
  __syncthreads();
#pragma unroll
  for (int yy = 0; yy < 4; ++yy) {
    int oc = blockIdx.x * 32 + ty + yy * 8;   // output row (= input col)
    dst[(size_t)oc * R + blockIdx.y * 32 + tx] = f2bf(tile[tx][ty + yy * 8]);
  }
}

// LayerNorm over D=768, fp32 math. One block per token. Two output variants.
__global__ __launch_bounds__(256) void ln_f32_kernel(const float* __restrict__ x,
    const float* __restrict__ g, const float* __restrict__ b, float* __restrict__ out) {
  const int t = blockIdx.x;
  const int tid = threadIdx.x;
  const float* row = x + (size_t)t * DM;
  float v0 = row[tid], v1 = row[tid + 256], v2 = row[tid + 512];
  float s = v0 + v1 + v2;
  float s2 = v0 * v0 + v1 * v1 + v2 * v2;
#pragma unroll
  for (int off = 32; off > 0; off >>= 1) {
    s += __shfl_down(s, off, 64);
    s2 += __shfl_down(s2, off, 64);
  }
  __shared__ float red[8];
  if ((tid & 63) == 0) { red[tid >> 6] = s; red[4 + (tid >> 6)] = s2; }
  __syncthreads();
  float S = red[0] + red[1] + red[2] + red[3];
  float S2 = red[4] + red[5] + red[6] + red[7];
  float mean = S * (1.0f / DM);
  float var = S2 * (1.0f / DM) - mean * mean;
  float rstd = rsqrtf(var + 1e-5f);
  float* orow = out + (size_t)t * DM;
  orow[tid]       = (v0 - mean) * rstd * g[tid]       + b[tid];
  orow[tid + 256] = (v1 - mean) * rstd * g[tid + 256] + b[tid + 256];
  orow[tid + 512] = (v2 - mean) * rstd * g[tid + 512] + b[tid + 512];
}

__global__ __launch_bounds__(256) void ln_bf16_kernel(const float* __restrict__ x,
    const float* __restrict__ g, const float* __restrict__ b, u16* __restrict__ out) {
  const int t = blockIdx.x;
  const int tid = threadIdx.x;
  const float* row = x + (size_t)t * DM;
  float v0 = row[tid], v1 = row[tid + 256], v2 = row[tid + 512];
  float s = v0 + v1 + v2;
  float s2 = v0 * v0 + v1 * v1 + v2 * v2;
#pragma unroll
  for (int off = 32; off > 0; off >>= 1) {
    s += __shfl_down(s, off, 64);
    s2 += __shfl_down(s2, off, 64);
  }
  __shared__ float red[8];
  if ((tid & 63) == 0) { red[tid >> 6] = s; red[4 + (tid >> 6)] = s2; }
  __syncthreads();
  float S = red[0] + red[1] + red[2] + red[3];
  float S2 = red[4] + red[5] + red[6] + red[7];
  float mean = S * (1.0f / DM);
  float var = S2 * (1.0f / DM) - mean * mean;
  float rstd = rsqrtf(var + 1e-5f);
  u16* orow = out + (size_t)t * DM;
  orow[tid]       = f2bf((v0 - mean) * rstd * g[tid]       + b[tid]);
  orow[tid + 256] = f2bf((v1 - mean) * rstd * g[tid + 256] + b[tid + 256]);
  orow[tid + 512] = f2bf((v2 - mean) * rstd * g[tid + 512] + b[tid + 512]);
}

// -------------------------------------------------------- fp32 GEMM mainloop
// C[128x128] = A[M][K] * B[N][K]^T, all fp32. 256 threads, 8x8 per thread.
// BK=16. lsA/lsB are [16][128] fp32 staged transposed (k-major).
// Fragments: rows = tm*8 + ii (broadcast); cols = (jj>>2)*64 + tn*4 + (jj&3)
// (two float4 groups, 2-way bank alias max = free). At the 8x8-tile LDS-pipe
// structural ceiling (~87 TF measured) -- do not re-tile without fixing VGPRs.
__device__ __forceinline__ void sgemm_mainloop(const float* __restrict__ A,
    const float* __restrict__ B, int lda, int ldb, int gm0, int gn0, int K,
    float (*lsA)[128], float (*lsB)[128], float acc[8][8]) {
  const int tid = threadIdx.x;
  const int srow = tid >> 1;          // 0..127
  const int skoff = (tid & 1) * 8;    // 0 or 8
  const int tm = tid >> 4, tn = tid & 15;
  const float* ga = A + (size_t)(gm0 + srow) * lda + skoff;
  const float* gb = B + (size_t)(gn0 + srow) * ldb + skoff;
  for (int k0 = 0; k0 < K; k0 += 16) {
    float4 a0 = *(const float4*)(ga);
    float4 a1 = *(const float4*)(ga + 4);
    float4 b0 = *(const float4*)(gb);
    float4 b1 = *(const float4*)(gb + 4);
    ga += 16; gb += 16;
    __syncthreads();   // previous compute done before overwrite
    lsA[skoff + 0][srow] = a0.x; lsA[skoff + 1][srow] = a0.y;
    lsA[skoff + 2][srow] = a0.z; lsA[skoff + 3][srow] = a0.w;
    lsA[skoff + 4][srow] = a1.x; lsA[skoff + 5][srow] = a1.y;
    lsA[skoff + 6][srow] = a1.z; lsA[skoff + 7][srow] = a1.w;
    lsB[skoff + 0][srow] = b0.x; lsB[skoff + 1][srow] = b0.y;
    lsB[skoff + 2][srow] = b0.z; lsB[skoff + 3][srow] = b0.w;
    lsB[skoff + 4][srow] = b1.x; lsB[skoff + 5][srow] = b1.y;
    lsB[skoff + 6][srow] = b1.z; lsB[skoff + 7][srow] = b1.w;
    __syncthreads();
#pragma unroll
    for (int k = 0; k < 16; ++k) {
      float4 av0 = *(const float4*)&lsA[k][tm * 8];
      float4 av1 = *(const float4*)&lsA[k][tm * 8 + 4];
      float4 bv0 = *(const float4*)&lsB[k][tn * 4];
      float4 bv1 = *(const float4*)&lsB[k][64 + tn * 4];
      float av[8] = {av0.x, av0.y, av0.z, av0.w, av1.x, av1.y, av1.z, av1.w};
      float bv[8] = {bv0.x, bv0.y, bv0.z, bv0.w, bv1.x, bv1.y, bv1.z, bv1.w};
#pragma unroll
      for (int i = 0; i < 8; ++i)
#pragma unroll
        for (int j = 0; j < 8; ++j)
          acc[i][j] = fmaf(av[i], bv[j], acc[i][j]);
    }
  }
}

// QKV fp32: A=x2f[T][768], B=in_proj_w[2304][768]; scatter to q/k/v [B,H,S,64] fp32
__global__ __launch_bounds__(256) void qkv_f32_kernel(const float* __restrict__ A,
    const float* __restrict__ Bw, const float* __restrict__ bias,
    float* __restrict__ qf, float* __restrict__ kf, float* __restrict__ vf) {
  __shared__ float lsA[16][128];
  __shared__ float lsB[16][128];
  const int gm0 = blockIdx.x * 128, gn0 = blockIdx.y * 128;
  float acc[8][8];
#pragma unroll
  for (int i = 0; i < 8; ++i)
#pragma unroll
    for (int j = 0; j < 8; ++j) acc[i][j] = 0.f;
  sgemm_mainloop(A, Bw, DM, DM, gm0, gn0, DM, lsA, lsB, acc);
  const int tm = threadIdx.x >> 4, tn = threadIdx.x & 15;
#pragma unroll
  for (int jj = 0; jj < 8; ++jj) {
    int col = gn0 + (jj >> 2) * 64 + tn * 4 + (jj & 3);
    int which = col / DM;
    int rem = col - which * DM;
    int hh = rem >> 6, dd = rem & 63;
    float bc = bias[col];
    float* dst = which == 0 ? qf : (which == 1 ? kf : vf);
#pragma unroll
    for (int ii = 0; ii < 8; ++ii) {
      int t = gm0 + tm * 8 + ii;
      int bb = t >> 9, ss = t & 511;
      dst[(((size_t)(bb * 12 + hh) * 512 + ss) << 6) + dd] = acc[ii][jj] + bc;
    }
  }
}

// Out-proj fp32: A=aof[T][768], B=out_proj_w[768][768]; + bias + residual -> xres
__global__ __launch_bounds__(256) void outproj_f32_kernel(const float* __restrict__ A,
    const float* __restrict__ Bw, const float* __restrict__ bias,
    const float* __restrict__ xin, float* __restrict__ xres) {
  __shared__ float lsA[16][128];
  __shared__ float lsB[16][128];
  const int gm0 = blockIdx.x * 128, gn0 = blockIdx.y * 128;
  float acc[8][8];
#pragma unroll
  for (int i = 0; i < 8; ++i)
#pragma unroll
    for (int j = 0; j < 8; ++j) acc[i][j] = 0.f;
  sgemm_mainloop(A, Bw, DM, DM, gm0, gn0, DM, lsA, lsB, acc);
  const int tm = threadIdx.x >> 4, tn = threadIdx.x & 15;
#pragma unroll
  for (int ii = 0; ii < 8; ++ii) {
    int t = gm0 + tm * 8 + ii;
#pragma unroll
    for (int jj = 0; jj < 8; ++jj) {
      int n = gn0 + (jj >> 2) * 64 + tn * 4 + (jj & 3);
      size_t off = (size_t)t * DM + n;
      xres[off] = acc[ii][jj] + bias[n] + xin[off];
    }
  }
}

// ------------------------------------------------------------ fp32 attention
// One thread per query row; block = 256 queries of one (b,h). K/V tiles of 64
// keys double-buffered in LDS via async global_load_lds (prefetch costs zero
// VGPRs -- the fix for the AGPR-demoted state blocking load pipelining).
// Compute reads are ds_read_b128 at wave-uniform addresses (broadcast, no
// bank conflicts). Arithmetic identical to the previous version (chunk-4
// online softmax, rare rescale), so numerics are bit-identical.
__global__ __launch_bounds__(256, 2) void attn_f32_kernel(const float* __restrict__ qb,
    const float* __restrict__ kb, const float* __restrict__ vb, float* __restrict__ ao) {
  __shared__ float kls[2][64 * 64];
  __shared__ float vls[2][64 * 64];
  const int tid = threadIdx.x;
  const int bh = blockIdx.x >> 1;
  const int sq = (blockIdx.x & 1) * 256 + tid;
  const size_t base = (size_t)bh * 512 * 64;
  const float* qp = qb + base + (size_t)sq * 64;
  float q[64];
#pragma unroll
  for (int i = 0; i < 16; ++i) {
    float4 t = ((const float4*)qp)[i];
    q[4 * i]     = t.x * 0.125f;   // fold 1/sqrt(64)
    q[4 * i + 1] = t.y * 0.125f;
    q[4 * i + 2] = t.z * 0.125f;
    q[4 * i + 3] = t.w * 0.125f;
  }
  float m = -1e30f, l = 0.f, o[64];
#pragma unroll
  for (int d = 0; d < 64; ++d) o[d] = 0.f;

  const float* kg = kb + base;
  const float* vg = vb + base;
  // stage tile t (64 keys x 64 dims fp32 = 16KB each for K and V) into buf b
  auto stage = [&](int t, int b) {
#pragma unroll
    for (int r = 0; r < 4; ++r) {
      gld16(kg + (size_t)t * 4096 + r * 1024 + tid * 4, &kls[b][r * 1024 + tid * 4]);
      gld16(vg + (size_t)t * 4096 + r * 1024 + tid * 4, &vls[b][r * 1024 + tid * 4]);
    }
  };

  stage(0, 0);
  __syncthreads();                       // drains vmcnt: tile 0 resident
  for (int t = 0; t < 8; ++t) {
    if (t + 1 < 8) stage(t + 1, (t + 1) & 1);   // async prefetch, zero VGPR cost
    const float4* kp = (const float4*)&kls[t & 1][0];
    const float4* vp = (const float4*)&vls[t & 1][0];
    for (int c = 0; c < 64; c += 4) {    // chunk of 4 keys
      const float4* kr = kp + c * 16;
      float s[4];
#pragma unroll
      for (int j = 0; j < 4; ++j) {
        float sa = 0.f, sb = 0.f;        // two chains per key
#pragma unroll
        for (int i = 0; i < 8; ++i) {
          float4 u = kr[j * 16 + i];
          float4 w = kr[j * 16 + 8 + i];
          sa = fmaf(q[4 * i],      u.x, sa);
          sa = fmaf(q[4 * i + 1],  u.y, sa);
          sa = fmaf(q[4 * i + 2],  u.z, sa);
          sa = fmaf(q[4 * i + 3],  u.w, sa);
          sb = fmaf(q[32 + 4 * i],     w.x, sb);
          sb = fmaf(q[32 + 4 * i + 1], w.y, sb);
          sb = fmaf(q[32 + 4 * i + 2], w.z, sb);
          sb = fmaf(q[32 + 4 * i + 3], w.w, sb);
        }
        s[j] = sa + sb;
      }
      float mx = fmaxf(fmaxf(s[0], s[1]), fmaxf(s[2], s[3]));
      if (mx > m) {                      // rare after warm-up
        float al = __expf(m - mx);       // first chunk: exp(-1e30)=0
        l *= al;
#pragma unroll
        for (int d = 0; d < 64; ++d) o[d] *= al;
        m = mx;
      }
      float p0 = __expf(s[0] - m);
      float p1 = __expf(s[1] - m);
      float p2 = __expf(s[2] - m);
      float p3 = __expf(s[3] - m);
      l += (p0 + p1) + (p2 + p3);
      const float4* vr = vp + c * 16;    // 4 V rows
#pragma unroll
      for (int i = 0; i < 16; ++i) {
        float4 u0 = vr[i];
        float4 u1 = vr[16 + i];
        float4 u2 = vr[32 + i];
        float4 u3 = vr[48 + i];
        float a = o[4 * i], b = o[4 * i + 1], c2 = o[4 * i + 2], d = o[4 * i + 3];
        a = fmaf(p0, u0.x, a); b = fmaf(p0, u0.y, b); c2 = fmaf(p0, u0.z, c2); d = fmaf(p0, u0.w, d);
        a = fmaf(p1, u1.x, a); b = fmaf(p1, u1.y, b); c2 = fmaf(p1, u1.z, c2); d = fmaf(p1, u1.w, d);
        a = fmaf(p2, u2.x, a); b = fmaf(p2, u2.y, b); c2 = fmaf(p2, u2.z, c2); d = fmaf(p2, u2.w, d);
        a = fmaf(p3, u3.x, a); b = fmaf(p3, u3.y, b); c2 = fmaf(p3, u3.z, c2); d = fmaf(p3, u3.w, d);
        o[4 * i] = a; o[4 * i + 1] = b; o[4 * i + 2] = c2; o[4 * i + 3] = d;
      }
    }
    __syncthreads();   // drains vmcnt (tile t+1 ready) + buf reuse safety
  }
  float inv = 1.0f / l;
  int b = bh / 12, h = bh - b * 12;
  float* outp = ao + ((size_t)(b * 512 + sq)) * DM + h * 64;
#pragma unroll
  for (int i = 0; i < 16; ++i) {
    float4 t;
    t.x = o[4 * i] * inv; t.y = o[4 * i + 1] * inv;
    t.z = o[4 * i + 2] * inv; t.w = o[4 * i + 3] * inv;
    ((float4*)outp)[i] = t;
  }
}

// ------------------------------------------------------------- bf16 MFMA core
__device__ __forceinline__ void gemm_mainloop(const u16* a0, const u16* a1,
                                              const u16* b0, const u16* b1,
                                              u16* lsA, u16* lsB,
                                              f32x4 acc[4][4], int ksteps) {
  const int tid = threadIdx.x;
  const int lane = tid & 63;
  const int wm = (tid >> 6) & 1, wn = tid >> 7;
  u16* la0 = lsA + tid * 8;
  u16* la1 = lsA + 2048 + tid * 8;
  u16* lb0 = lsB + tid * 8;
  u16* lb1 = lsB + 2048 + tid * 8;
  const u16* ra = lsA + (wm * 64 + (lane & 15)) * 32 + (lane >> 4) * 8;
  const u16* rb = lsB + (wn * 64 + (lane & 15)) * 32 + (lane >> 4) * 8;
  for (int ks = 0; ks < ksteps; ++ks) {
    gld16(a0, la0); gld16(a1, la1);
    gld16(b0, lb0); gld16(b1, lb1);
    a0 += 32; a1 += 32; b0 += 32; b1 += 32;
    __syncthreads();              // drains vmcnt(0): LDS tile complete
    short8 af[4], bfr[4];
#pragma unroll
    for (int i = 0; i < 4; ++i) af[i] = *(const short8*)(ra + i * 512);
#pragma unroll
    for (int j = 0; j < 4; ++j) bfr[j] = *(const short8*)(rb + j * 512);
#pragma unroll
    for (int i = 0; i < 4; ++i)
#pragma unroll
      for (int j = 0; j < 4; ++j)
        acc[i][j] = __builtin_amdgcn_mfma_f32_16x16x32_bf16(af[i], bfr[j], acc[i][j], 0, 0, 0);
    __syncthreads();              // protect LDS before next overwrite
  }
}

#define GEMM_PROLOGUE()                                             \
  const int tid = threadIdx.x;                                      \
  const int r = tid >> 2, c8 = (tid & 3) * 8;                       \
  f32x4 acc[4][4];                                                  \
  {                                                                 \
    f32x4 z = {0.f, 0.f, 0.f, 0.f};                                 \
    _Pragma("unroll") for (int i = 0; i < 4; ++i)                   \
      _Pragma("unroll") for (int j = 0; j < 4; ++j) acc[i][j] = z;  \
  }

#define GEMM_EPI_IDX()                                              \
  const int lane = tid & 63;                                        \
  const int wm = (tid >> 6) & 1, wn = tid >> 7;                     \
  const int ln = lane & 15, q4 = (lane >> 4) * 4;

// ------------------------------------------------------------------- router
// fp32 LN2 recompute + logits. One wave per token; lane 0 picks top-2.
__global__ __launch_bounds__(256) void router_kernel(const float* __restrict__ xres,
    const float* __restrict__ g, const float* __restrict__ bnb,
    const float* __restrict__ Wr, const float* __restrict__ br,
    int* __restrict__ counts, int* __restrict__ idx, float* __restrict__ wgt) {
  const int wv = threadIdx.x >> 6, lane = threadIdx.x & 63;
  const int t = blockIdx.x * 4 + wv;
  const float* row = xres + (size_t)t * DM;
  float xv[12];
  float s = 0.f, s2 = 0.f;
#pragma unroll
  for (int i = 0; i < 12; ++i) {
    float v = row[lane + i * 64];
    xv[i] = v; s += v; s2 += v * v;
  }
#pragma unroll
  for (int off = 32; off > 0; off >>= 1) {
    s += __shfl_xor(s, off, 64);
    s2 += __shfl_xor(s2, off, 64);
  }
  float mean = s * (1.0f / DM);
  float rstd = rsqrtf(s2 * (1.0f / DM) - mean * mean + 1e-5f);
#pragma unroll
  for (int i = 0; i < 12; ++i)
    xv[i] = (xv[i] - mean) * rstd * g[lane + i * 64] + bnb[lane + i * 64];
  float lg[8];
#pragma unroll
  for (int e = 0; e < 8; ++e) {
    float p = 0.f;
#pragma unroll
    for (int i = 0; i < 12; ++i) p = fmaf(xv[i], Wr[e * DM + lane + i * 64], p);
#pragma unroll
    for (int off = 32; off > 0; off >>= 1) p += __shfl_xor(p, off, 64);
    lg[e] = p;
  }
  if (lane == 0) {
    float mx = -1e30f;
#pragma unroll
    for (int e = 0; e < 8; ++e) { lg[e] += br[e]; mx = fmaxf(mx, lg[e]); }
    float ex[8];
#pragma unroll
    for (int e = 0; e < 8; ++e) ex[e] = __expf(lg[e] - mx);
    int e0 = 0;
#pragma unroll
    for (int e = 1; e < 8; ++e) if (ex[e] > ex[e0]) e0 = e;  // ties -> lowest idx
    int e1 = (e0 == 0) ? 1 : 0;
#pragma unroll
    for (int e = 0; e < 8; ++e) if (e != e0 && ex[e] > ex[e1]) e1 = e;
    float denom = 1.0f / (ex[e0] + ex[e1]);
    int s0 = atomicAdd(counts + e0, 1);
    idx[e0 * TOK + s0] = (t << 1);
    wgt[e0 * TOK + s0] = ex[e0] * denom;
    int s1 = atomicAdd(counts + e1, 1);
    idx[e1 * TOK + s1] = (t << 1) | 1;
    wgt[e1 * TOK + s1] = ex[e1] * denom;
  }
}

// exclusive prefix over 8 expert counts (sum is always 32768)
__global__ void offs_kernel(const int* __restrict__ counts, int* __restrict__ offs) {
  if (threadIdx.x == 0) {
    int acc = 0;
    for (int e = 0; e < NEXP; ++e) { offs[e] = acc; acc += counts[e]; }
  }
}

// ------------------------------------------------------------------ MoE GEMMs
__global__ __launch_bounds__(256) void moe_gemm1_kernel(const u16* __restrict__ xm,
    const u16* __restrict__ w1T, const float* __restrict__ b1,
    const int* __restrict__ idx, const int* __restrict__ counts,
    const int* __restrict__ offs, u16* __restrict__ hbuf, int pass) {
  const int e = blockIdx.z;
  const int cnt = counts[e];
  const int gm0 = blockIdx.x * 128;
  if (gm0 >= cnt) return;
  __shared__ __align__(16) u16 lsA[4096];
  __shared__ __align__(16) u16 lsB[4096];
  const int gn0 = blockIdx.y * 128;           // within [0, DH)
  GEMM_PROLOGUE();
  const int s0 = gm0 + r, s1 = gm0 + 64 + r;
  const int t0 = (s0 < cnt) ? (idx[e * TOK + s0] >> 1) : 0;
  const int t1 = (s1 < cnt) ? (idx[e * TOK + s1] >> 1) : 0;
  const u16* a0 = xm + (size_t)t0 * DM + c8;
  const u16* a1 = xm + (size_t)t1 * DM + c8;
  const u16* Be = w1T + (size_t)e * DFF * DM + (size_t)pass * DH * DM;
  const u16* b0 = Be + (size_t)(gn0 + r) * DM + c8;
  const u16* b1p = Be + (size_t)(gn0 + 64 + r) * DM + c8;
  gemm_mainloop(a0, a1, b0, b1p, lsA, lsB, acc, DM / 32);
  GEMM_EPI_IDX();
  const int base = offs[e];
#pragma unroll
  for (int i = 0; i < 4; ++i) {
#pragma unroll
    for (int rr = 0; rr < 4; ++rr) {
      int slot = gm0 + wm * 64 + i * 16 + q4 + rr;
      if (slot >= cnt) continue;
      u16* hrow = hbuf + (size_t)(base + slot) * DH;
#pragma unroll
      for (int j = 0; j < 4; ++j) {
        int n = gn0 + wn * 64 + j * 16 + ln;
        float v = acc[i][j][rr] + b1[e * DFF + pass * DH + n];
        float gg = 0.5f * v * (1.0f + erff(v * 0.70710678118654752f));  // exact gelu
        hrow[n] = f2bf(gg);
      }
    }
  }
}

__global__ __launch_bounds__(256) void moe_gemm2_kernel(const u16* __restrict__ hbuf,
    const u16* __restrict__ w2T, const float* __restrict__ b2,
    const int* __restrict__ idx, const int* __restrict__ counts,
    const int* __restrict__ offs, const float* __restrict__ wgt,
    float* __restrict__ out, int pass) {
  const int e = blockIdx.z;
  const int cnt = counts[e];
  const int gm0 = blockIdx.x * 128;
  if (gm0 >= cnt) return;
  __shared__ __align__(16) u16 lsA[4096];
  __shared__ __align__(16) u16 lsB[4096];
  const int gn0 = blockIdx.y * 128;
  GEMM_PROLOGUE();
  const int base = offs[e];
  int row0 = base + gm0 + r;      if (row0 > ROWS - 1) row0 = ROWS - 1;
  int row1 = base + gm0 + 64 + r; if (row1 > ROWS - 1) row1 = ROWS - 1;
  const u16* a0 = hbuf + (size_t)row0 * DH + c8;
  const u16* a1 = hbuf + (size_t)row1 * DH + c8;
  const u16* Be = w2T + (size_t)e * DM * DFF + (size_t)pass * DH;
  const u16* b0 = Be + (size_t)(gn0 + r) * DFF + c8;
  const u16* b1p = Be + (size_t)(gn0 + 64 + r) * DFF + c8;
  gemm_mainloop(a0, a1, b0, b1p, lsA, lsB, acc, DH / 32);
  GEMM_EPI_IDX();
#pragma unroll
  for (int i = 0; i < 4; ++i) {
#pragma unroll
    for (int rr = 0; rr < 4; ++rr) {
      int slot = gm0 + wm * 64 + i * 16 + q4 + rr;
      if (slot >= cnt) continue;
      int ent = idx[e * TOK + slot];
      int t = ent >> 1;
      float wv = wgt[e * TOK + slot];
#pragma unroll
      for (int j = 0; j < 4; ++j) {
        int n = gn0 + wn * 64 + j * 16 + ln;
        float bb = pass ? 0.f : b2[e * DM + n];   // bias once (pass 0)
        atomicAdd(out + (size_t)t * DM + n, wv * (acc[i][j][rr] + bb));
      }
    }
  }
}

// -------------------------------------------------------------------- launch
extern "C" void kernel_launch(void* const* d_in, const int* in_sizes, int n_in,
                              void* d_out, int out_size, void* d_ws, size_t ws_size,
                              hipStream_t stream) {
  const float* x     = (const float*)d_in[0];
  const float* ln1_g = (const float*)d_in[1];
  const float* ln1_b = (const float*)d_in[2];
  const float* in_w  = (const float*)d_in[3];
  const float* in_b  = (const float*)d_in[4];
  const float* out_w = (const float*)d_in[5];
  const float* out_b = (const float*)d_in[6];
  const float* ln2_g = (const float*)d_in[7];
  const float* ln2_b = (const float*)d_in[8];
  const float* rtr_w = (const float*)d_in[9];
  const float* rtr_b = (const float*)d_in[10];
  const float* w1    = (const float*)d_in[11];
  const float* b1    = (const float*)d_in[12];
  const float* w2    = (const float*)d_in[13];
  const float* b2    = (const float*)d_in[14];
  float* xres = (float*)d_out;                       // residual lives in d_out

  char* p = (char*)d_ws;
  auto take = [&](size_t bytes) { char* r = p; p += (bytes + 255) & ~(size_t)255; return r; };
  int* idx    = (int*)take((size_t)NEXP * TOK * 4);       // 0.5 MB
  float* wgt  = (float*)take((size_t)NEXP * TOK * 4);     // 0.5 MB
  int* counts = (int*)take(64);
  int* offs   = (int*)take(64);
  char* arena = take((size_t)4 * TOK * DM * 4);           // 201.3 MB, phase-aliased
  // phase A (attention, all fp32):
  float* x2f = (float*)(arena);                            // 50.3 MB (LN1 out; later aof)
  float* qf  = (float*)(arena + (size_t)1 * TOK * DM * 4);
  float* kf  = (float*)(arena + (size_t)2 * TOK * DM * 4);
  float* vf  = (float*)(arena + (size_t)3 * TOK * DM * 4);
  float* aof = x2f;                                        // x2f dead after qkv
  // phase B (MoE, after outproj; overlays phase A exactly):
  u16* w1T  = (u16*)(arena);                               // 37.7 MB [E][Dff][D]
  u16* w2T  = (u16*)(arena + (size_t)NEXP * DFF * DM * 2); // 37.7 MB [E][D][Dff]
  u16* xm   = (u16*)(arena + (size_t)2 * NEXP * DFF * DM * 2);          // 25.2 MB
  u16* hbuf = (u16*)(arena + (size_t)2 * NEXP * DFF * DM * 2 + (size_t)TOK * DM * 2); // 100.7 MB
  // total ws use: ~202.4 MB

  hipMemsetAsync(counts, 0, 32, stream);

  // ---- attention path, fully fp32 (router decisions must match fp32 ref) ----
  ln_f32_kernel<<<TOK, 256, 0, stream>>>(x, ln1_g, ln1_b, x2f);
  qkv_f32_kernel<<<dim3(TOK / 128, 3 * DM / 128), 256, 0, stream>>>(x2f, in_w, in_b, qf, kf, vf);
  attn_f32_kernel<<<32 * 12 * 2, 256, 0, stream>>>(qf, kf, vf, aof);
  outproj_f32_kernel<<<dim3(TOK / 128, DM / 128), 256, 0, stream>>>(aof, out_w, out_b, x, xres);

  // ---- MoE path, bf16 MFMA (post-router noise is within threshold) ----
  transpose_cast_kernel<<<dim3(DFF / 32, DM / 32, NEXP), dim3(32, 8), 0, stream>>>(w1, w1T, DM, DFF);
  transpose_cast_kernel<<<dim3(DM / 32, DFF / 32, NEXP), dim3(32, 8), 0, stream>>>(w2, w2T, DFF, DM);
  ln_bf16_kernel<<<TOK, 256, 0, stream>>>(xres, ln2_g, ln2_b, xm);
  router_kernel<<<TOK / 4, 256, 0, stream>>>(xres, ln2_g, ln2_b, rtr_w, rtr_b, counts, idx, wgt);
  offs_kernel<<<1, 64, 0, stream>>>(counts, offs);

  for (int pass = 0; pass < 2; ++pass) {
    moe_gemm1_kernel<<<dim3(TOK / 128, DH / 128, NEXP), 256, 0, stream>>>(
        xm, w1T, b1, idx, counts, offs, hbuf, pass);
    moe_gemm2_kernel<<<dim3(TOK / 128, DM / 128, NEXP), 256, 0, stream>>>(
        hbuf, w2T, b2, idx, counts, offs, wgt, xres, pass);
  }
}